// Round 15
// baseline (555.410 us; speedup 1.0000x reference)
//
#include <hip/hip_runtime.h>

#define BB 64
#define SS 2048
#define FF 256
#define CC 32
#define CH 64   // chunks per sequence (32 steps each)

typedef unsigned u32x2 __attribute__((ext_vector_type(2)));

__device__ __forceinline__ void plswap16(int a_in, int& x, int& y) {
#if __has_builtin(__builtin_amdgcn_permlane16_swap)
    u32x2 r = __builtin_amdgcn_permlane16_swap((unsigned)a_in, (unsigned)a_in, false, false);
    x = (int)r[0]; y = (int)r[1];
#else
    int xx = a_in, yy;
    asm volatile("v_mov_b32 %0, %1" : "=v"(yy) : "v"(a_in));
    asm volatile("v_permlane16_swap_b32 %0, %1" : "+v"(xx), "+v"(yy));
    x = xx; y = yy;
#endif
}
__device__ __forceinline__ void plswap32(int a_in, int& x, int& y) {
#if __has_builtin(__builtin_amdgcn_permlane32_swap)
    u32x2 r = __builtin_amdgcn_permlane32_swap((unsigned)a_in, (unsigned)a_in, false, false);
    x = (int)r[0]; y = (int)r[1];
#else
    int xx = a_in, yy;
    asm volatile("v_mov_b32 %0, %1" : "=v"(yy) : "v"(a_in));
    asm volatile("v_permlane32_swap_b32 %0, %1" : "+v"(xx), "+v"(yy));
    x = xx; y = yy;
#endif
}

#if __has_builtin(__builtin_amdgcn_mov_dpp)
#define ROT1(d, s, K) d = __builtin_amdgcn_mov_dpp(s, 0x120 + K, 0xF, 0xF, false)
#else
#define ROT1(d, s, K) d = __builtin_amdgcn_update_dpp(s, s, 0x120 + K, 0xF, 0xF, false)
#endif
#define ROTALL(arr, s) \
    arr[0] = s;        \
    ROT1(arr[1], s, 1);  ROT1(arr[2], s, 2);  ROT1(arr[3], s, 3);  \
    ROT1(arr[4], s, 4);  ROT1(arr[5], s, 5);  ROT1(arr[6], s, 6);  \
    ROT1(arr[7], s, 7);  ROT1(arr[8], s, 8);  ROT1(arr[9], s, 9);  \
    ROT1(arr[10], s, 10); ROT1(arr[11], s, 11); ROT1(arr[12], s, 12); \
    ROT1(arr[13], s, 13); ROT1(arr[14], s, 14); ROT1(arr[15], s, 15)

__device__ __forceinline__ float fmax3_(float a, float b, float c) { return fmaxf(fmaxf(a, b), c); }

// STEP2: r11's proven asm step (bit-exact chain step).
#define STEP2_ASM(avar, evar)                                                       \
    do {                                                                            \
        float x_, b_, q0_, q1_, q2_, q3_, q4_, q5_, q6_, q7_,                       \
              q8_, q9_, q10_, q11_, q12_, q13_, q14_, q15_;                         \
        asm volatile(                                                               \
            "v_mov_b32 %[x], %[aa]\n\t"                                             \
            "s_nop 1\n\t"                                                           \
            "v_permlane16_swap_b32 %[x], %[aa]\n\t"                                 \
            "s_nop 0\n\t"                                                           \
            "v_cndmask_b32 %[bb], %[aa], %[x], %[m16]\n\t"                          \
            "s_nop 1\n\t"                                                           \
            "v_add_f32 %[q0], %[bb], %[t0]\n\t"                                     \
            "v_add_f32_dpp %[q1], %[bb], %[t1] row_ror:1 row_mask:0xf bank_mask:0xf\n\t"  \
            "v_add_f32_dpp %[q2], %[bb], %[t2] row_ror:2 row_mask:0xf bank_mask:0xf\n\t"  \
            "v_add_f32_dpp %[q3], %[bb], %[t3] row_ror:3 row_mask:0xf bank_mask:0xf\n\t"  \
            "v_add_f32_dpp %[q4], %[bb], %[t4] row_ror:4 row_mask:0xf bank_mask:0xf\n\t"  \
            "v_add_f32_dpp %[q5], %[bb], %[t5] row_ror:5 row_mask:0xf bank_mask:0xf\n\t"  \
            "v_add_f32_dpp %[q6], %[bb], %[t6] row_ror:6 row_mask:0xf bank_mask:0xf\n\t"  \
            "v_add_f32_dpp %[q7], %[bb], %[t7] row_ror:7 row_mask:0xf bank_mask:0xf\n\t"  \
            "v_add_f32_dpp %[q8], %[bb], %[t8] row_ror:8 row_mask:0xf bank_mask:0xf\n\t"  \
            "v_add_f32_dpp %[q9], %[bb], %[t9] row_ror:9 row_mask:0xf bank_mask:0xf\n\t"  \
            "v_add_f32_dpp %[q10], %[bb], %[t10] row_ror:10 row_mask:0xf bank_mask:0xf\n\t" \
            "v_add_f32_dpp %[q11], %[bb], %[t11] row_ror:11 row_mask:0xf bank_mask:0xf\n\t" \
            "v_add_f32_dpp %[q12], %[bb], %[t12] row_ror:12 row_mask:0xf bank_mask:0xf\n\t" \
            "v_add_f32_dpp %[q13], %[bb], %[t13] row_ror:13 row_mask:0xf bank_mask:0xf\n\t" \
            "v_add_f32_dpp %[q14], %[bb], %[t14] row_ror:14 row_mask:0xf bank_mask:0xf\n\t" \
            "v_add_f32_dpp %[q15], %[bb], %[t15] row_ror:15 row_mask:0xf bank_mask:0xf\n\t" \
            "v_max3_f32 %[q0], %[q0], %[q1], %[q2]\n\t"                             \
            "v_max3_f32 %[q3], %[q3], %[q4], %[q5]\n\t"                             \
            "v_max3_f32 %[q6], %[q6], %[q7], %[q8]\n\t"                             \
            "v_max3_f32 %[q9], %[q9], %[q10], %[q11]\n\t"                           \
            "v_max3_f32 %[q12], %[q12], %[q13], %[q14]\n\t"                         \
            "v_max3_f32 %[q0], %[q0], %[q3], %[q6]\n\t"                             \
            "v_max3_f32 %[q9], %[q9], %[q12], %[q15]\n\t"                           \
            "v_max_f32 %[q0], %[q0], %[q9]\n\t"                                     \
            "v_mov_b32 %[x], %[q0]\n\t"                                             \
            "s_nop 1\n\t"                                                           \
            "v_permlane32_swap_b32 %[x], %[q0]\n\t"                                 \
            "s_nop 0\n\t"                                                           \
            "v_max_f32 %[q0], %[q0], %[x]\n\t"                                      \
            "v_add_f32 %[aa], %[q0], %[ee]\n\t"                                     \
            : [aa] "+v"(avar), [x] "=&v"(x_), [bb] "=&v"(b_),                       \
              [q0] "=&v"(q0_), [q1] "=&v"(q1_), [q2] "=&v"(q2_), [q3] "=&v"(q3_),   \
              [q4] "=&v"(q4_), [q5] "=&v"(q5_), [q6] "=&v"(q6_), [q7] "=&v"(q7_),   \
              [q8] "=&v"(q8_), [q9] "=&v"(q9_), [q10] "=&v"(q10_),                  \
              [q11] "=&v"(q11_), [q12] "=&v"(q12_), [q13] "=&v"(q13_),              \
              [q14] "=&v"(q14_), [q15] "=&v"(q15_)                                  \
            : [ee] "v"(evar), [t0] "v"(Ti[0]), [t1] "v"(Ti[1]), [t2] "v"(Ti[2]),    \
              [t3] "v"(Ti[3]), [t4] "v"(Ti[4]), [t5] "v"(Ti[5]), [t6] "v"(Ti[6]),   \
              [t7] "v"(Ti[7]), [t8] "v"(Ti[8]), [t9] "v"(Ti[9]), [t10] "v"(Ti[10]), \
              [t11] "v"(Ti[11]), [t12] "v"(Ti[12]), [t13] "v"(Ti[13]),              \
              [t14] "v"(Ti[14]), [t15] "v"(Ti[15]),                                 \
              [m16] "s"(mask16));                                                   \
    } while (0)

// ---------------------------------------------------------------------------
// FUSED emis + fwd. Grid 2112 x 256:
//   blocks 0..2047  = emis tiles, CHUNK-MAJOR (i = g*64 + b): every batch's
//                     early tiles finish in the first occupancy round.
//   blocks 2048..2111 = fwd chains (1 wave active); each gates chunk C on
//                     prog[b] >= min(C+2, 32) (device-scope acquire).
// No deadlock: 64 fwd blocks < 256 CUs; emis blocks never wait.
// Alpha stored v4-batched in-place over em (window disjoint from +8 prefetch).
// ---------------------------------------------------------------------------
__global__ __launch_bounds__(256) void fused_emis_fwd(const float* __restrict__ X,
                                                      const float* __restrict__ W,
                                                      const float* __restrict__ bias,
                                                      const float* __restrict__ T,
                                                      const float* __restrict__ startT,
                                                      const float* __restrict__ endT,
                                                      float* __restrict__ em,
                                                      float* __restrict__ out,
                                                      int* __restrict__ prog) {
    __shared__ __align__(16) float wsh[32 * 260];

    if (blockIdx.x < 2048) {
        // ---------------- emis role (bit-exact r14 emis v2) ----------------
        const int tid = threadIdx.x;
        const int g = blockIdx.x >> 6;
        const int b = blockIdx.x & 63;
        const long rowbase = (long)b * SS + (long)g * 64;

        const float4* Wg = (const float4*)W;
#pragma unroll
        for (int i = 0; i < 8; ++i) {
            int idx = tid + i * 256;
            int r = idx >> 6, c4 = idx & 63;
            *(float4*)&wsh[r * 260 + c4 * 4] = Wg[idx];
        }
        __syncthreads();

        const int rp = tid >> 3;
        const int cgp = tid & 7;
        const long r0 = rowbase + 2 * rp, r1 = r0 + 1;
        const float4* X0 = (const float4*)(X + r0 * FF);
        const float4* X1 = (const float4*)(X + r1 * FF);

        float acc0[4] = {0.f, 0.f, 0.f, 0.f};
        float acc1[4] = {0.f, 0.f, 0.f, 0.f};

#pragma unroll 8
        for (int k4 = 0; k4 < 64; ++k4) {
            float4 xa = X0[k4];
            float4 xb = X1[k4];
#pragma unroll
            for (int jj = 0; jj < 4; ++jj) {
                float4 w = *(const float4*)&wsh[(cgp + 8 * jj) * 260 + k4 * 4];
                acc0[jj] = fmaf(xa.x, w.x, acc0[jj]);
                acc0[jj] = fmaf(xa.y, w.y, acc0[jj]);
                acc0[jj] = fmaf(xa.z, w.z, acc0[jj]);
                acc0[jj] = fmaf(xa.w, w.w, acc0[jj]);
                acc1[jj] = fmaf(xb.x, w.x, acc1[jj]);
                acc1[jj] = fmaf(xb.y, w.y, acc1[jj]);
                acc1[jj] = fmaf(xb.z, w.z, acc1[jj]);
                acc1[jj] = fmaf(xb.w, w.w, acc1[jj]);
            }
        }
#pragma unroll
        for (int jj = 0; jj < 4; ++jj) {
            int c = cgp + 8 * jj;
            float bj = bias[c];
            em[r0 * CC + c] = acc0[jj] + bj;
            em[r1 * CC + c] = acc1[jj] + bj;
        }

        __syncthreads();
        __threadfence();                     // make tile stores device-visible
        if (tid == 0)
            __hip_atomic_fetch_add(&prog[b], 1, __ATOMIC_RELEASE, __HIP_MEMORY_SCOPE_AGENT);
        return;
    }

    // ------------------------------ fwd role ------------------------------
    if (threadIdx.x >= 64) return;
    const int l = threadIdx.x;
    const int b = blockIdx.x - 2048;
    const int j = l & 31;
    const int h = l >> 5;

    int p0, p1;
    plswap16(j, p0, p1);
    const bool c16 = (((p0 >> 4) & 1) == h);
    const int pm = c16 ? p0 : p1;
    int mk[16];
    ROTALL(mk, pm);

    const unsigned long long mask16 = __ballot(c16);

    float Ti[16];
#pragma unroll
    for (int k = 0; k < 16; ++k) Ti[k] = T[mk[k] * CC + j];

    int* pb = prog + b;
    auto pollb = [&](int need) {
        while (__hip_atomic_load(pb, __ATOMIC_ACQUIRE, __HIP_MEMORY_SCOPE_AGENT) < need)
            __builtin_amdgcn_s_sleep(2);
    };

    float* eb = em + (long)b * SS * CC;
    float4* ev4 = (float4*)eb;

    pollb(2);                                // rows 0..127 available

    float eq[8];
#pragma unroll
    for (int v = 0; v < 8; ++v) eq[v] = eb[v * 32 + j];

    float4 av;
    float a = startT[j] + eq[0];             // alpha_0
    av.x = a;                                // slot t=0
    eq[0] = eb[8 * 32 + j];

    int t = 1;
    for (int g = 0; g < 254; ++g) {
        if ((g & 7) == 0) {
            int need = (g >> 3) + 2;
            if (need > 32) need = 32;
            pollb(need);
        }
        // 8 steps, base t = 1+8g (t%4 pattern: 1,2,3,0,1,2,3,0)
        STEP2_ASM(a, eq[t & 7]); av.y = a; eq[t & 7] = eb[(t + 8) * 32 + j]; ++t;
        STEP2_ASM(a, eq[t & 7]); av.z = a; eq[t & 7] = eb[(t + 8) * 32 + j]; ++t;
        STEP2_ASM(a, eq[t & 7]); av.w = a; ev4[(t >> 2) * 32 + j] = av;
        eq[t & 7] = eb[(t + 8) * 32 + j]; ++t;
        STEP2_ASM(a, eq[t & 7]); av.x = a; eq[t & 7] = eb[(t + 8) * 32 + j]; ++t;
        STEP2_ASM(a, eq[t & 7]); av.y = a; eq[t & 7] = eb[(t + 8) * 32 + j]; ++t;
        STEP2_ASM(a, eq[t & 7]); av.z = a; eq[t & 7] = eb[(t + 8) * 32 + j]; ++t;
        STEP2_ASM(a, eq[t & 7]); av.w = a; ev4[(t >> 2) * 32 + j] = av;
        eq[t & 7] = eb[(t + 8) * 32 + j]; ++t;
        STEP2_ASM(a, eq[t & 7]); av.x = a; eq[t & 7] = eb[(t + 8) * 32 + j]; ++t;
    }
    // t = 2033..2039 (refills read rows 2041..2047; pattern 1,2,3,0,1,2,3)
    STEP2_ASM(a, eq[t & 7]); av.y = a; eq[t & 7] = eb[(t + 8) * 32 + j]; ++t;
    STEP2_ASM(a, eq[t & 7]); av.z = a; eq[t & 7] = eb[(t + 8) * 32 + j]; ++t;
    STEP2_ASM(a, eq[t & 7]); av.w = a; ev4[(t >> 2) * 32 + j] = av;
    eq[t & 7] = eb[(t + 8) * 32 + j]; ++t;
    STEP2_ASM(a, eq[t & 7]); av.x = a; eq[t & 7] = eb[(t + 8) * 32 + j]; ++t;
    STEP2_ASM(a, eq[t & 7]); av.y = a; eq[t & 7] = eb[(t + 8) * 32 + j]; ++t;
    STEP2_ASM(a, eq[t & 7]); av.z = a; eq[t & 7] = eb[(t + 8) * 32 + j]; ++t;
    STEP2_ASM(a, eq[t & 7]); av.w = a; ev4[(t >> 2) * 32 + j] = av; ++t;
    // t = 2040..2047 (no refills; pattern 0,1,2,3,0,1,2,3)
    STEP2_ASM(a, eq[t & 7]); av.x = a; ++t;
    STEP2_ASM(a, eq[t & 7]); av.y = a; ++t;
    STEP2_ASM(a, eq[t & 7]); av.z = a; ++t;
    STEP2_ASM(a, eq[t & 7]); av.w = a; ev4[(t >> 2) * 32 + j] = av; ++t;
    STEP2_ASM(a, eq[t & 7]); av.x = a; ++t;
    STEP2_ASM(a, eq[t & 7]); av.y = a; ++t;
    STEP2_ASM(a, eq[t & 7]); av.z = a; ++t;
    STEP2_ASM(a, eq[t & 7]); av.w = a; ev4[(t >> 2) * 32 + j] = av; ++t;

    float v = a + endT[j];
    int idx = j;
#pragma unroll
    for (int d = 1; d <= 16; d <<= 1) {
        float ovv = __shfl_xor(v, d);
        int   oii = __shfl_xor(idx, d);
        bool c = (ovv > v) || (ovv == v && oii < idx);
        v = c ? ovv : v;
        idx = c ? oii : idx;
    }
    if (l == 0) {
        out[b] = v;
        out[BB + (long)b * SS + (SS - 1)] = (float)idx;
    }
}

// ---------------------------------------------------------------------------
// bp_compose — CH=64 chunks x 32 steps, exact argmax semantics; alpha read as
// 8 upfront float4 (v4 layout written by fwd). launch_bounds(64,2): no spills.
// ---------------------------------------------------------------------------
__global__ __launch_bounds__(64, 2) void bp_compose(const float* __restrict__ alpha,
                                                    const float* __restrict__ T,
                                                    unsigned* __restrict__ bp,
                                                    unsigned char* __restrict__ G) {
    const int l = threadIdx.x;
    const int j = l & 31;
    const int h = l >> 5;
    const int b = blockIdx.x >> 6;
    const int k = blockIdx.x & 63;

    int p0, p1;
    plswap16(j, p0, p1);
    const bool c16 = (((p0 >> 4) & 1) == h);
    const int pm = c16 ? p0 : p1;
    int mk[16];
    ROTALL(mk, pm);
    int q0p, q1p;
    plswap32(l, q0p, q1p);
    const bool pick0 = (q0p == (l ^ 32));

    float Ti[16];
    unsigned Bk[16];
#pragma unroll
    for (int kk = 0; kk < 16; ++kk) {
        Ti[kk] = T[mk[kk] * CC + j];
        Bk[kk] = 1u << mk[kk];
    }

    const float4* A4 = (const float4*)(alpha + (long)b * SS * CC);
    float4 aq4[8];
#pragma unroll
    for (int gg = 0; gg < 8; ++gg) aq4[gg] = A4[(8 * k + gg) * 32 + j];

    unsigned sr[8];
#pragma unroll
    for (int p = 0; p < 8; ++p) sr[p] = 0u;

#pragma unroll
    for (int gg = 0; gg < 8; ++gg) {
#pragma unroll
        for (int v = 0; v < 4; ++v) {
            const int u = gg * 4 + v;
            float av = (v == 0) ? aq4[gg].x : (v == 1) ? aq4[gg].y
                     : (v == 2) ? aq4[gg].z : aq4[gg].w;

            int x, y;
            plswap16(__float_as_int(av), x, y);
            int base = c16 ? x : y;
            int rot[16];
            ROTALL(rot, base);
            float s[16];
#pragma unroll
            for (int kk = 0; kk < 16; ++kk) s[kk] = __int_as_float(rot[kk]) + Ti[kk];

            float m0 = fmax3_(s[0], s[1], s[2]);
            float m1 = fmax3_(s[3], s[4], s[5]);
            float m2 = fmax3_(s[6], s[7], s[8]);
            float m3 = fmax3_(s[9], s[10], s[11]);
            float m4 = fmax3_(s[12], s[13], s[14]);
            float mv = fmaxf(fmax3_(m0, m1, m2), fmax3_(m3, m4, s[15]));

            int xm, ym;
            plswap32(__float_as_int(mv), xm, ym);
            float ov = __int_as_float(pick0 ? xm : ym);
            float gv = fmaxf(mv, ov);

            unsigned c0 = (s[0] == gv) ? Bk[0] : 0u,   c1 = (s[1] == gv) ? Bk[1] : 0u;
            unsigned c2 = (s[2] == gv) ? Bk[2] : 0u,   c3 = (s[3] == gv) ? Bk[3] : 0u;
            unsigned c4 = (s[4] == gv) ? Bk[4] : 0u,   c5 = (s[5] == gv) ? Bk[5] : 0u;
            unsigned c6 = (s[6] == gv) ? Bk[6] : 0u,   c7 = (s[7] == gv) ? Bk[7] : 0u;
            unsigned c8 = (s[8] == gv) ? Bk[8] : 0u,   c9 = (s[9] == gv) ? Bk[9] : 0u;
            unsigned c10 = (s[10] == gv) ? Bk[10] : 0u, c11 = (s[11] == gv) ? Bk[11] : 0u;
            unsigned c12 = (s[12] == gv) ? Bk[12] : 0u, c13 = (s[13] == gv) ? Bk[13] : 0u;
            unsigned c14 = (s[14] == gv) ? Bk[14] : 0u, c15 = (s[15] == gv) ? Bk[15] : 0u;
            unsigned msk = ((c0 | c1 | c2) | (c3 | c4 | c5)) |
                           ((c6 | c7 | c8) | (c9 | c10 | c11)) |
                           ((c12 | c13 | c14) | c15);

            int xk, yk;
            plswap32((int)msk, xk, yk);
            unsigned om = (unsigned)(pick0 ? xk : yk);
            int wi = __builtin_ctz(msk | om);

            if (u == 31 && k == CH - 1) wi = j;   // bp slot 2047 = identity
            sr[u >> 2] |= (unsigned)wi << ((u & 3) * 8);
        }
    }

#pragma unroll
    for (int p = 0; p < 8; ++p)
        bp[((unsigned)(8 * k + p) * BB + b) * CC + j] = sr[p];

    int g = j;
#pragma unroll
    for (int rel = 31; rel >= 0; --rel) {
        unsigned dw = (unsigned)__builtin_amdgcn_ds_bpermute((g | (l & 32)) << 2,
                                                             (int)sr[rel >> 2]);
        g = (int)((dw >> ((rel & 3) * 8)) & 31u);
    }
    G[(b * CH + k) * 32 + j] = (unsigned char)g;
}

// ---------------------------------------------------------------------------
// bt_scan — 2 blocks x 32 batches; G staged in LDS (64 KB/block).
// ---------------------------------------------------------------------------
__global__ __launch_bounds__(64) void bt_scan(const unsigned char* __restrict__ G,
                                              const float* __restrict__ out,
                                              int* __restrict__ tagB) {
    __shared__ unsigned char Gs[32 * CH * 32];
    const int l = threadIdx.x;
    const int bbase = blockIdx.x * 32;
    const float4* Gg = (const float4*)(G + (size_t)bbase * CH * 32);
    float4* Gls = (float4*)Gs;
#pragma unroll
    for (int i = 0; i < 64; ++i) Gls[l + i * 64] = Gg[l + i * 64];
    __syncthreads();

    if (l < 32) {
        const int b = bbase + l;
        int cur = (int)out[BB + (long)b * SS + (SS - 1)];
        for (int k = CH - 1; k >= 0; --k) {
            cur = Gs[(l * CH + k) * 32 + cur];
            tagB[b * CH + k] = cur;
        }
    }
}

// ---------------------------------------------------------------------------
// bt_emit — 4096 blocks, each re-walks its 32-step chunk.
// ---------------------------------------------------------------------------
__global__ __launch_bounds__(64, 4) void bt_emit(const unsigned* __restrict__ bp,
                                                 const int* __restrict__ tagB,
                                                 const float* __restrict__ outR,
                                                 float* __restrict__ out) {
    const int l = threadIdx.x;
    const int b = blockIdx.x >> 6;
    const int k = blockIdx.x & 63;

    unsigned sr[8];
#pragma unroll
    for (int p = 0; p < 8; ++p) sr[p] = bp[((unsigned)(8 * k + p) * BB + b) * CC + (l & 31)];

    int start = (k == CH - 1) ? (int)outR[BB + (long)b * SS + (SS - 1)]
                              : tagB[b * CH + k + 1];
    int g = start, cap = start;
#pragma unroll
    for (int rel = 31; rel >= 0; --rel) {
        unsigned dw = (unsigned)__builtin_amdgcn_ds_bpermute((g | (l & 32)) << 2,
                                                             (int)sr[rel >> 2]);
        g = (int)((dw >> ((rel & 3) * 8)) & 31u);
        cap = (l == rel) ? g : cap;
    }
    if (l < 32) out[BB + (long)b * SS + k * 32 + l] = (float)cap;
}

// ---------------------------------------------------------------------------
extern "C" void kernel_launch(void* const* d_in, const int* in_sizes, int n_in,
                              void* d_out, int out_size, void* d_ws, size_t ws_size,
                              hipStream_t stream) {
    const float* X      = (const float*)d_in[0];
    const float* W      = (const float*)d_in[1];
    const float* bias   = (const float*)d_in[2];
    const float* T      = (const float*)d_in[3];
    const float* startT = (const float*)d_in[4];
    const float* endT   = (const float*)d_in[5];
    float* out = (float*)d_out;

    float*    em = (float*)d_ws;                                        // 16 MB (e -> alpha-v4 in-place)
    unsigned* bp = (unsigned*)((char*)d_ws + (size_t)BB * SS * CC * 4); // 4 MB @ 16 MB
    unsigned char* G    = (unsigned char*)d_ws + (20u << 20);           // 128 KB @ 20 MB
    int*           tagB = (int*)((char*)d_ws + (20u << 20) + 131072);   // 16 KB
    int*           prog = (int*)((char*)d_ws + (20u << 20) + 163840);   // 256 B

    hipMemsetAsync(prog, 0, BB * sizeof(int), stream);
    fused_emis_fwd<<<2048 + BB, 256, 0, stream>>>(X, W, bias, T, startT, endT, em, out, prog);
    bp_compose<<<BB * CH, 64, 0, stream>>>(em, T, bp, G);
    bt_scan<<<2, 64, 0, stream>>>(G, out, tagB);
    bt_emit<<<BB * CH, 64, 0, stream>>>(bp, tagB, out, out);
}

// Round 16
// 260.251 us; speedup vs baseline: 2.1341x; 2.1341x over previous
//
#include <hip/hip_runtime.h>

#define BB 64
#define SS 2048
#define FF 256
#define CC 32
#define CH 64   // chunks per sequence (32 steps each)

typedef unsigned u32x2 __attribute__((ext_vector_type(2)));

// Two-result permlane swaps (builtin returns {vdst, vsrc} in distinct regs).
__device__ __forceinline__ void plswap16(int a_in, int& x, int& y) {
#if __has_builtin(__builtin_amdgcn_permlane16_swap)
    u32x2 r = __builtin_amdgcn_permlane16_swap((unsigned)a_in, (unsigned)a_in, false, false);
    x = (int)r[0]; y = (int)r[1];
#else
    int xx = a_in, yy;
    asm volatile("v_mov_b32 %0, %1" : "=v"(yy) : "v"(a_in));
    asm volatile("v_permlane16_swap_b32 %0, %1" : "+v"(xx), "+v"(yy));
    x = xx; y = yy;
#endif
}
__device__ __forceinline__ void plswap32(int a_in, int& x, int& y) {
#if __has_builtin(__builtin_amdgcn_permlane32_swap)
    u32x2 r = __builtin_amdgcn_permlane32_swap((unsigned)a_in, (unsigned)a_in, false, false);
    x = (int)r[0]; y = (int)r[1];
#else
    int xx = a_in, yy;
    asm volatile("v_mov_b32 %0, %1" : "=v"(yy) : "v"(a_in));
    asm volatile("v_permlane32_swap_b32 %0, %1" : "+v"(xx), "+v"(yy));
    x = xx; y = yy;
#endif
}

#if __has_builtin(__builtin_amdgcn_mov_dpp)
#define ROT1(d, s, K) d = __builtin_amdgcn_mov_dpp(s, 0x120 + K, 0xF, 0xF, false)
#else
#define ROT1(d, s, K) d = __builtin_amdgcn_update_dpp(s, s, 0x120 + K, 0xF, 0xF, false)
#endif
#define ROTALL(arr, s) \
    arr[0] = s;        \
    ROT1(arr[1], s, 1);  ROT1(arr[2], s, 2);  ROT1(arr[3], s, 3);  \
    ROT1(arr[4], s, 4);  ROT1(arr[5], s, 5);  ROT1(arr[6], s, 6);  \
    ROT1(arr[7], s, 7);  ROT1(arr[8], s, 8);  ROT1(arr[9], s, 9);  \
    ROT1(arr[10], s, 10); ROT1(arr[11], s, 11); ROT1(arr[12], s, 12); \
    ROT1(arr[13], s, 13); ROT1(arr[14], s, 14); ROT1(arr[15], s, 15)

__device__ __forceinline__ float fmax3_(float a, float b, float c) { return fmaxf(fmaxf(a, b), c); }

// ---------------------------------------------------------------------------
// Kernel 1: emissions GEMM v2 (proven r14).
//  * X NOT staged (per-thread global stream; 8 lanes/row broadcast via L1).
//  * Only W in LDS (33 KB) -> 4 blocks/CU TLP.
//  * Thread cols {c, c+8, c+16, c+24}: conflict-free W reads.
//  * FMA order per output unchanged -> bit-identical emissions.
// ---------------------------------------------------------------------------
__global__ __launch_bounds__(256) void emis_kernel(const float* __restrict__ X,
                                                   const float* __restrict__ W,
                                                   const float* __restrict__ bias,
                                                   float* __restrict__ em) {
    __shared__ __align__(16) float wsh[32 * 260];
    const int tid = threadIdx.x;
    const long rowbase = (long)blockIdx.x * 64;

    const float4* Wg = (const float4*)W;
#pragma unroll
    for (int i = 0; i < 8; ++i) {
        int idx = tid + i * 256;          // 0..2047 float4 slots (32 rows x 64)
        int r = idx >> 6, c4 = idx & 63;
        *(float4*)&wsh[r * 260 + c4 * 4] = Wg[idx];
    }
    __syncthreads();

    const int rp = tid >> 3;              // 0..31 -> rows 2rp, 2rp+1
    const int cgp = tid & 7;              // cols {cgp, cgp+8, cgp+16, cgp+24}
    const long r0 = rowbase + 2 * rp, r1 = r0 + 1;
    const float4* X0 = (const float4*)(X + r0 * FF);
    const float4* X1 = (const float4*)(X + r1 * FF);

    float acc0[4] = {0.f, 0.f, 0.f, 0.f};
    float acc1[4] = {0.f, 0.f, 0.f, 0.f};

#pragma unroll 8
    for (int k4 = 0; k4 < 64; ++k4) {
        float4 xa = X0[k4];
        float4 xb = X1[k4];
#pragma unroll
        for (int jj = 0; jj < 4; ++jj) {
            float4 w = *(const float4*)&wsh[(cgp + 8 * jj) * 260 + k4 * 4];
            acc0[jj] = fmaf(xa.x, w.x, acc0[jj]);
            acc0[jj] = fmaf(xa.y, w.y, acc0[jj]);
            acc0[jj] = fmaf(xa.z, w.z, acc0[jj]);
            acc0[jj] = fmaf(xa.w, w.w, acc0[jj]);
            acc1[jj] = fmaf(xb.x, w.x, acc1[jj]);
            acc1[jj] = fmaf(xb.y, w.y, acc1[jj]);
            acc1[jj] = fmaf(xb.z, w.z, acc1[jj]);
            acc1[jj] = fmaf(xb.w, w.w, acc1[jj]);
        }
    }
#pragma unroll
    for (int jj = 0; jj < 4; ++jj) {
        int c = cgp + 8 * jj;
        float bj = bias[c];
        em[r0 * CC + c] = acc0[jj] + bj;
        em[r1 * CC + c] = acc1[jj] + bj;
    }
}

// ---------------------------------------------------------------------------
// STEP2: r11's proven asm step (trimmed tail: mov+swap32+max — exact since
// {own,partner} under commutative fmax covers the global max).
// ---------------------------------------------------------------------------
#define STEP2_ASM(avar, evar)                                                       \
    do {                                                                            \
        float x_, b_, q0_, q1_, q2_, q3_, q4_, q5_, q6_, q7_,                       \
              q8_, q9_, q10_, q11_, q12_, q13_, q14_, q15_;                         \
        asm volatile(                                                               \
            "v_mov_b32 %[x], %[aa]\n\t"                                             \
            "s_nop 1\n\t"                                                           \
            "v_permlane16_swap_b32 %[x], %[aa]\n\t"                                 \
            "s_nop 0\n\t"                                                           \
            "v_cndmask_b32 %[bb], %[aa], %[x], %[m16]\n\t"                          \
            "s_nop 1\n\t"                                                           \
            "v_add_f32 %[q0], %[bb], %[t0]\n\t"                                     \
            "v_add_f32_dpp %[q1], %[bb], %[t1] row_ror:1 row_mask:0xf bank_mask:0xf\n\t"  \
            "v_add_f32_dpp %[q2], %[bb], %[t2] row_ror:2 row_mask:0xf bank_mask:0xf\n\t"  \
            "v_add_f32_dpp %[q3], %[bb], %[t3] row_ror:3 row_mask:0xf bank_mask:0xf\n\t"  \
            "v_add_f32_dpp %[q4], %[bb], %[t4] row_ror:4 row_mask:0xf bank_mask:0xf\n\t"  \
            "v_add_f32_dpp %[q5], %[bb], %[t5] row_ror:5 row_mask:0xf bank_mask:0xf\n\t"  \
            "v_add_f32_dpp %[q6], %[bb], %[t6] row_ror:6 row_mask:0xf bank_mask:0xf\n\t"  \
            "v_add_f32_dpp %[q7], %[bb], %[t7] row_ror:7 row_mask:0xf bank_mask:0xf\n\t"  \
            "v_add_f32_dpp %[q8], %[bb], %[t8] row_ror:8 row_mask:0xf bank_mask:0xf\n\t"  \
            "v_add_f32_dpp %[q9], %[bb], %[t9] row_ror:9 row_mask:0xf bank_mask:0xf\n\t"  \
            "v_add_f32_dpp %[q10], %[bb], %[t10] row_ror:10 row_mask:0xf bank_mask:0xf\n\t" \
            "v_add_f32_dpp %[q11], %[bb], %[t11] row_ror:11 row_mask:0xf bank_mask:0xf\n\t" \
            "v_add_f32_dpp %[q12], %[bb], %[t12] row_ror:12 row_mask:0xf bank_mask:0xf\n\t" \
            "v_add_f32_dpp %[q13], %[bb], %[t13] row_ror:13 row_mask:0xf bank_mask:0xf\n\t" \
            "v_add_f32_dpp %[q14], %[bb], %[t14] row_ror:14 row_mask:0xf bank_mask:0xf\n\t" \
            "v_add_f32_dpp %[q15], %[bb], %[t15] row_ror:15 row_mask:0xf bank_mask:0xf\n\t" \
            "v_max3_f32 %[q0], %[q0], %[q1], %[q2]\n\t"                             \
            "v_max3_f32 %[q3], %[q3], %[q4], %[q5]\n\t"                             \
            "v_max3_f32 %[q6], %[q6], %[q7], %[q8]\n\t"                             \
            "v_max3_f32 %[q9], %[q9], %[q10], %[q11]\n\t"                           \
            "v_max3_f32 %[q12], %[q12], %[q13], %[q14]\n\t"                         \
            "v_max3_f32 %[q0], %[q0], %[q3], %[q6]\n\t"                             \
            "v_max3_f32 %[q9], %[q9], %[q12], %[q15]\n\t"                           \
            "v_max_f32 %[q0], %[q0], %[q9]\n\t"                                     \
            "v_mov_b32 %[x], %[q0]\n\t"                                             \
            "s_nop 1\n\t"                                                           \
            "v_permlane32_swap_b32 %[x], %[q0]\n\t"                                 \
            "s_nop 0\n\t"                                                           \
            "v_max_f32 %[q0], %[q0], %[x]\n\t"                                      \
            "v_add_f32 %[aa], %[q0], %[ee]\n\t"                                     \
            : [aa] "+v"(avar), [x] "=&v"(x_), [bb] "=&v"(b_),                       \
              [q0] "=&v"(q0_), [q1] "=&v"(q1_), [q2] "=&v"(q2_), [q3] "=&v"(q3_),   \
              [q4] "=&v"(q4_), [q5] "=&v"(q5_), [q6] "=&v"(q6_), [q7] "=&v"(q7_),   \
              [q8] "=&v"(q8_), [q9] "=&v"(q9_), [q10] "=&v"(q10_),                  \
              [q11] "=&v"(q11_), [q12] "=&v"(q12_), [q13] "=&v"(q13_),              \
              [q14] "=&v"(q14_), [q15] "=&v"(q15_)                                  \
            : [ee] "v"(evar), [t0] "v"(Ti[0]), [t1] "v"(Ti[1]), [t2] "v"(Ti[2]),    \
              [t3] "v"(Ti[3]), [t4] "v"(Ti[4]), [t5] "v"(Ti[5]), [t6] "v"(Ti[6]),   \
              [t7] "v"(Ti[7]), [t8] "v"(Ti[8]), [t9] "v"(Ti[9]), [t10] "v"(Ti[10]), \
              [t11] "v"(Ti[11]), [t12] "v"(Ti[12]), [t13] "v"(Ti[13]),              \
              [t14] "v"(Ti[14]), [t15] "v"(Ti[15]),                                 \
              [m16] "s"(mask16));                                                   \
    } while (0)

// ---------------------------------------------------------------------------
// Kernel 2: forward alpha chain — r11's proven fwd4 (64 blocks x 1 wave).
// e via 8-deep global register queue; alpha stored in-place over em.
// ---------------------------------------------------------------------------
__global__ __launch_bounds__(64, 1) void viterbi_fwd4(float* __restrict__ em,
                                                      const float* __restrict__ T,
                                                      const float* __restrict__ startT,
                                                      const float* __restrict__ endT,
                                                      float* __restrict__ out) {
    const int l = threadIdx.x;
    const int b = blockIdx.x;
    const int j = l & 31;
    const int h = l >> 5;

    int p0, p1;
    plswap16(j, p0, p1);
    const bool c16 = (((p0 >> 4) & 1) == h);
    const int pm = c16 ? p0 : p1;
    int mk[16];
    ROTALL(mk, pm);

    const unsigned long long mask16 = __ballot(c16);

    float Ti[16];
#pragma unroll
    for (int k = 0; k < 16; ++k) Ti[k] = T[mk[k] * CC + j];

    float* eb = em + (long)b * SS * CC;

    float eq[8];
#pragma unroll
    for (int v = 0; v < 8; ++v) eq[v] = eb[v * 32 + j];

    float a = startT[j] + eq[0];           // alpha_0
    eb[j] = a;
    eq[0] = eb[8 * 32 + j];

    int t = 1;
    for (int g = 0; g < 254; ++g) {
#pragma unroll
        for (int u = 0; u < 8; ++u) {
            STEP2_ASM(a, eq[t & 7]);
            eb[t * 32 + j] = a;
            eq[t & 7] = eb[(t + 8) * 32 + j];
            ++t;
        }
    }
#pragma unroll
    for (int u = 0; u < 7; ++u) {
        STEP2_ASM(a, eq[t & 7]);
        eb[t * 32 + j] = a;
        eq[t & 7] = eb[(t + 8) * 32 + j];
        ++t;
    }
#pragma unroll
    for (int u = 0; u < 8; ++u) {
        STEP2_ASM(a, eq[t & 7]);
        eb[t * 32 + j] = a;
        ++t;
    }

    float v = a + endT[j];
    int idx = j;
#pragma unroll
    for (int d = 1; d <= 16; d <<= 1) {
        float ovv = __shfl_xor(v, d);
        int   oii = __shfl_xor(idx, d);
        bool c = (ovv > v) || (ovv == v && oii < idx);
        v = c ? ovv : v;
        idx = c ? oii : idx;
    }
    if (l == 0) {
        out[b] = v;
        out[BB + (long)b * SS + (SS - 1)] = (float)idx;
    }
}

// ---------------------------------------------------------------------------
// Kernel 3: bp_compose — CH=64 chunks x 32 steps, exact argmax semantics.
// launch_bounds(64,2): no spills.
// ---------------------------------------------------------------------------
__global__ __launch_bounds__(64, 2) void bp_compose(const float* __restrict__ alpha,
                                                    const float* __restrict__ T,
                                                    unsigned* __restrict__ bp,
                                                    unsigned char* __restrict__ G) {
    const int l = threadIdx.x;
    const int j = l & 31;
    const int h = l >> 5;
    const int b = blockIdx.x >> 6;
    const int k = blockIdx.x & 63;

    int p0, p1;
    plswap16(j, p0, p1);
    const bool c16 = (((p0 >> 4) & 1) == h);
    const int pm = c16 ? p0 : p1;
    int mk[16];
    ROTALL(mk, pm);
    int q0p, q1p;
    plswap32(l, q0p, q1p);
    const bool pick0 = (q0p == (l ^ 32));

    float Ti[16];
    unsigned Bk[16];
#pragma unroll
    for (int kk = 0; kk < 16; ++kk) {
        Ti[kk] = T[mk[kk] * CC + j];
        Bk[kk] = 1u << mk[kk];
    }

    const float* A = alpha + (long)b * SS * CC;
    const int u0 = k << 5;

    float aq[8];
#pragma unroll
    for (int v = 0; v < 8; ++v) aq[v] = A[(u0 + v) * CC + j];

    unsigned sr[8];
#pragma unroll
    for (int p = 0; p < 8; ++p) sr[p] = 0u;

#pragma unroll
    for (int g8 = 0; g8 < 4; ++g8) {
#pragma unroll
        for (int v = 0; v < 8; ++v) {
            const int u = g8 * 8 + v;
            float av = aq[v];
            if (g8 < 3) aq[v] = A[(u0 + (g8 + 1) * 8 + v) * CC + j];

            int x, y;
            plswap16(__float_as_int(av), x, y);
            int base = c16 ? x : y;
            int rot[16];
            ROTALL(rot, base);
            float s[16];
#pragma unroll
            for (int kk = 0; kk < 16; ++kk) s[kk] = __int_as_float(rot[kk]) + Ti[kk];

            float m0 = fmax3_(s[0], s[1], s[2]);
            float m1 = fmax3_(s[3], s[4], s[5]);
            float m2 = fmax3_(s[6], s[7], s[8]);
            float m3 = fmax3_(s[9], s[10], s[11]);
            float m4 = fmax3_(s[12], s[13], s[14]);
            float mv = fmaxf(fmax3_(m0, m1, m2), fmax3_(m3, m4, s[15]));

            int xm, ym;
            plswap32(__float_as_int(mv), xm, ym);
            float ov = __int_as_float(pick0 ? xm : ym);
            float gv = fmaxf(mv, ov);

            unsigned c0 = (s[0] == gv) ? Bk[0] : 0u,   c1 = (s[1] == gv) ? Bk[1] : 0u;
            unsigned c2 = (s[2] == gv) ? Bk[2] : 0u,   c3 = (s[3] == gv) ? Bk[3] : 0u;
            unsigned c4 = (s[4] == gv) ? Bk[4] : 0u,   c5 = (s[5] == gv) ? Bk[5] : 0u;
            unsigned c6 = (s[6] == gv) ? Bk[6] : 0u,   c7 = (s[7] == gv) ? Bk[7] : 0u;
            unsigned c8 = (s[8] == gv) ? Bk[8] : 0u,   c9 = (s[9] == gv) ? Bk[9] : 0u;
            unsigned c10 = (s[10] == gv) ? Bk[10] : 0u, c11 = (s[11] == gv) ? Bk[11] : 0u;
            unsigned c12 = (s[12] == gv) ? Bk[12] : 0u, c13 = (s[13] == gv) ? Bk[13] : 0u;
            unsigned c14 = (s[14] == gv) ? Bk[14] : 0u, c15 = (s[15] == gv) ? Bk[15] : 0u;
            unsigned msk = ((c0 | c1 | c2) | (c3 | c4 | c5)) |
                           ((c6 | c7 | c8) | (c9 | c10 | c11)) |
                           ((c12 | c13 | c14) | c15);

            int xk, yk;
            plswap32((int)msk, xk, yk);
            unsigned om = (unsigned)(pick0 ? xk : yk);
            int wi = __builtin_ctz(msk | om);

            if (u == 31 && k == CH - 1) wi = j;   // bp slot 2047 = identity
            sr[u >> 2] |= (unsigned)wi << ((u & 3) * 8);
        }
    }

#pragma unroll
    for (int p = 0; p < 8; ++p)
        bp[((unsigned)(8 * k + p) * BB + b) * CC + j] = sr[p];

    int g = j;
#pragma unroll
    for (int rel = 31; rel >= 0; --rel) {
        unsigned dw = (unsigned)__builtin_amdgcn_ds_bpermute((g | (l & 32)) << 2,
                                                             (int)sr[rel >> 2]);
        g = (int)((dw >> ((rel & 3) * 8)) & 31u);
    }
    G[(b * CH + k) * 32 + j] = (unsigned char)g;
}

// ---------------------------------------------------------------------------
// Kernel 4: bt_scan — 2 blocks x 32 batches; G staged in LDS (64 KB/block).
// ---------------------------------------------------------------------------
__global__ __launch_bounds__(64) void bt_scan(const unsigned char* __restrict__ G,
                                              const float* __restrict__ out,
                                              int* __restrict__ tagB) {
    __shared__ unsigned char Gs[32 * CH * 32];
    const int l = threadIdx.x;
    const int bbase = blockIdx.x * 32;
    const float4* Gg = (const float4*)(G + (size_t)bbase * CH * 32);
    float4* Gls = (float4*)Gs;
#pragma unroll
    for (int i = 0; i < 64; ++i) Gls[l + i * 64] = Gg[l + i * 64];
    __syncthreads();

    if (l < 32) {
        const int b = bbase + l;
        int cur = (int)out[BB + (long)b * SS + (SS - 1)];
        for (int k = CH - 1; k >= 0; --k) {
            cur = Gs[(l * CH + k) * 32 + cur];
            tagB[b * CH + k] = cur;
        }
    }
}

// ---------------------------------------------------------------------------
// Kernel 5: bt_emit — 4096 blocks, each re-walks its 32-step chunk.
// ---------------------------------------------------------------------------
__global__ __launch_bounds__(64, 4) void bt_emit(const unsigned* __restrict__ bp,
                                                 const int* __restrict__ tagB,
                                                 const float* __restrict__ outR,
                                                 float* __restrict__ out) {
    const int l = threadIdx.x;
    const int b = blockIdx.x >> 6;
    const int k = blockIdx.x & 63;

    unsigned sr[8];
#pragma unroll
    for (int p = 0; p < 8; ++p) sr[p] = bp[((unsigned)(8 * k + p) * BB + b) * CC + (l & 31)];

    int start = (k == CH - 1) ? (int)outR[BB + (long)b * SS + (SS - 1)]
                              : tagB[b * CH + k + 1];
    int g = start, cap = start;
#pragma unroll
    for (int rel = 31; rel >= 0; --rel) {
        unsigned dw = (unsigned)__builtin_amdgcn_ds_bpermute((g | (l & 32)) << 2,
                                                             (int)sr[rel >> 2]);
        g = (int)((dw >> ((rel & 3) * 8)) & 31u);
        cap = (l == rel) ? g : cap;
    }
    if (l < 32) out[BB + (long)b * SS + k * 32 + l] = (float)cap;
}

// ---------------------------------------------------------------------------
extern "C" void kernel_launch(void* const* d_in, const int* in_sizes, int n_in,
                              void* d_out, int out_size, void* d_ws, size_t ws_size,
                              hipStream_t stream) {
    const float* X      = (const float*)d_in[0];
    const float* W      = (const float*)d_in[1];
    const float* bias   = (const float*)d_in[2];
    const float* T      = (const float*)d_in[3];
    const float* startT = (const float*)d_in[4];
    const float* endT   = (const float*)d_in[5];
    float* out = (float*)d_out;

    float*    em = (float*)d_ws;                                        // 16 MB (e -> alpha in-place)
    unsigned* bp = (unsigned*)((char*)d_ws + (size_t)BB * SS * CC * 4); // 4 MB @ 16 MB
    unsigned char* G    = (unsigned char*)d_ws + (20u << 20);           // 128 KB @ 20 MB
    int*           tagB = (int*)((char*)d_ws + (20u << 20) + 131072);   // 16 KB

    emis_kernel<<<(BB * SS) / 64, 256, 0, stream>>>(X, W, bias, em);
    viterbi_fwd4<<<BB, 64, 0, stream>>>(em, T, startT, endT, out);
    bp_compose<<<BB * CH, 64, 0, stream>>>(em, T, bp, G);
    bt_scan<<<2, 64, 0, stream>>>(G, out, tagB);
    bt_emit<<<BB * CH, 64, 0, stream>>>(bp, tagB, out, out);
}